// Round 1
// baseline (9554.054 us; speedup 1.0000x reference)
//
#include <hip/hip_runtime.h>
#include <cstdint>

#define B_  128
#define T_  1024
#define DIN 13
#define HS  256
#define N0  77
#define N1  51
#define N2  128

// gates: K = 13 (x) + 1 (pad) + 256 (h) = 270 -> padded pairs K2G = 136
#define K2G 136
#define QG  34
#define NRG 1024

#define K0   90
#define K2_0 48
#define Q0   12
#define NR0  308

#define K1   128
#define K2_1 64
#define Q1   16
#define NR1  204

#define KL2  179
#define K2_2 96
#define Q2   24
#define NR2  512

typedef _Float16 h2_t __attribute__((ext_vector_type(2)));

static __device__ __forceinline__ uint32_t pk2(float a, float b) {
  h2_t v; v.x = (_Float16)a; v.y = (_Float16)b;
  return __builtin_bit_cast(uint32_t, v);
}
static __device__ __forceinline__ float dot2f(uint32_t w, uint32_t z, float acc) {
#if __has_builtin(__builtin_amdgcn_fdot2)
  return __builtin_amdgcn_fdot2(__builtin_bit_cast(h2_t, w), __builtin_bit_cast(h2_t, z), acc, false);
#else
  h2_t a = __builtin_bit_cast(h2_t, w), b = __builtin_bit_cast(h2_t, z);
  return acc + (float)a.x * (float)b.x + (float)a.y * (float)b.y;
#endif
}
static __device__ __forceinline__ float dot8f(uint4 w, uint4 z, float acc) {
  acc = dot2f(w.x, z.x, acc);
  acc = dot2f(w.y, z.y, acc);
  acc = dot2f(w.z, z.z, acc);
  acc = dot2f(w.w, z.w, acc);
  return acc;
}
static __device__ __forceinline__ float sigf(float x) { return 1.f / (1.f + expf(-x)); }

// ---------------- prep kernels: f32 -> packed f16, transposed quad-interleaved ----------------

__global__ void prep_gates(const float* __restrict__ Wih, const float* __restrict__ Whh,
                           uint32_t* __restrict__ out) {
  int id = blockIdx.x * blockDim.x + threadIdx.x;
  if (id >= K2G * NRG) return;
  int k2 = id >> 10, row = id & (NRG - 1);
  float v[2];
#pragma unroll
  for (int j = 0; j < 2; ++j) {
    int k = 2 * k2 + j;
    float val = 0.f;
    if (k < DIN) val = Wih[row * DIN + k];
    else if (k >= 14 && k < 14 + HS) val = Whh[row * HS + (k - 14)];
    v[j] = val;
  }
  out[((k2 >> 2) * NRG + row) * 4 + (k2 & 3)] = pk2(v[0], v[1]);
}

__global__ void prep_cfc(const float* __restrict__ Wf1, const float* __restrict__ Wf2,
                         const float* __restrict__ Wta, const float* __restrict__ Wtb,
                         const float* __restrict__ mask,
                         int nh, int nin, int NR, int K2pad, uint32_t* __restrict__ out) {
  int id = blockIdx.x * blockDim.x + threadIdx.x;
  if (id >= NR * K2pad) return;
  int k2 = id / NR, r = id % NR;
  int mat = r / nh, o = r % nh;
  const float* W = (mat == 0) ? Wf1 : (mat == 1) ? Wf2 : (mat == 2) ? Wta : Wtb;
  int K = nin + nh;
  float v[2];
#pragma unroll
  for (int j = 0; j < 2; ++j) {
    int k = 2 * k2 + j;
    float val = 0.f;
    if (k < K) {
      val = W[o * K + k];
      if (mat < 2) val *= mask[o * K + k];
    }
    v[j] = val;
  }
  out[((k2 >> 2) * NR + r) * 4 + (k2 & 3)] = pk2(v[0], v[1]);
}

// ---------------- persistent recurrent kernel ----------------

struct SM {
  uint4 zg[QG];          // packed gates input [x|pad|h]
  uint4 z0[Q0];
  uint4 z1[Q1];
  uint4 z2[Q2];
  uint4 ld0[Q0 * NR0];   // LDS-resident l0 weights
  uint4 ld1[Q1 * NR1];   // LDS-resident l1 weights
  float xt[16];
  float lstm_h[HS];
  float hprev[HS];       // [l0 out | l1 out | l2 out] = recurrent h
  float garr[4 * HS];
  float ffb[4][128];
  float cb0[NR0];
  float cb1[NR1];
  float cb2[NR2];
  float hw[12][132];     // head weights, padded stride vs bank conflicts
  float hb[12];
};

struct Args {
  const float* x;
  const float* Wih; const float* Whh; const float* bih; const float* bhh;
  const float* W0[4]; const float* b0[4]; const float* m0;
  const float* W1[4]; const float* b1[4]; const float* m1;
  const float* W2[4]; const float* b2[4]; const float* m2;
  const float* gW; const float* gb; const float* aW; const float* ab;
  const float* uW; const float* ub;
  const uint4* wsG; const uint4* wsL0; const uint4* wsL1; const uint4* wsL2;
  float* out;
};

template <bool PK>
__global__ __launch_bounds__(512, 1) void rnn_persist(Args A) {
  extern __shared__ char smraw[];
  SM& sm = *(SM*)smraw;
  const int tid = threadIdx.x;
  const int b = blockIdx.x;

  // ---- startup: biases, head weights, state init, LDS-resident weights ----
  for (int i = tid; i < NR0; i += 512) sm.cb0[i] = A.b0[i / N0][i % N0];
  for (int i = tid; i < NR1; i += 512) sm.cb1[i] = A.b1[i / N1][i % N1];
  for (int i = tid; i < NR2; i += 512) sm.cb2[i] = A.b2[i / N2][i % N2];
  for (int i = tid; i < 12 * 128; i += 512) {
    int r = i >> 7, k = i & 127;
    sm.hw[r][k] = (r < 3) ? A.gW[r * 128 + k]
                : (r < 6) ? A.aW[(r - 3) * 128 + k]
                          : A.uW[(r - 6) * 128 + k];
  }
  if (tid < 12) sm.hb[tid] = (tid < 3) ? A.gb[tid] : (tid < 6) ? A.ab[tid - 3] : A.ub[tid - 6];
  for (int i = tid; i < HS; i += 512) sm.hprev[i] = 0.f;
  {
    uint32_t* zz = (uint32_t*)sm.zg;
    for (int i = tid; i < (QG + Q0 + Q1 + Q2) * 4; i += 512) zz[i] = 0u;
  }
  if (PK) {
    for (int i = tid; i < Q0 * NR0; i += 512) sm.ld0[i] = A.wsL0[i];
    for (int i = tid; i < Q1 * NR1; i += 512) sm.ld1[i] = A.wsL1[i];
  }
  float bga = A.bih[tid] + A.bhh[tid];
  float bgb = A.bih[tid + 512] + A.bhh[tid + 512];
  float c_r = 0.f;
  __syncthreads();

  uint32_t* zgu = (uint32_t*)sm.zg;
  uint32_t* z0u = (uint32_t*)sm.z0;
  uint32_t* z1u = (uint32_t*)sm.z1;
  uint32_t* z2u = (uint32_t*)sm.z2;

  const float* xb = A.x + (size_t)b * T_ * DIN;
  float* outP = A.out;
  const size_t UNC_OFF = (size_t)B_ * T_ * 6;

  for (int t = 0; t < T_; ++t) {
    const float* xp = xb + (size_t)t * DIN;
    if (tid < DIN) sm.xt[tid] = xp[tid];
    if (PK && tid < 7) {
      float a0 = xp[2 * tid];
      float a1 = (tid == 6) ? 0.f : xp[2 * tid + 1];
      zgu[tid] = pk2(a0, a1);
    }
    __syncthreads();

    // ---- gates: rows tid and tid+512 ----
    float aa = bga, ab = bgb;
    if (PK) {
#pragma unroll 4
      for (int q = 0; q < QG; ++q) {
        uint4 z = sm.zg[q];
        uint4 wa = A.wsG[q * NRG + tid];
        uint4 wb = A.wsG[q * NRG + 512 + tid];
        aa = dot8f(wa, z, aa);
        ab = dot8f(wb, z, ab);
      }
    } else {
      for (int k = 0; k < DIN; ++k) {
        float xv = sm.xt[k];
        aa += A.Wih[tid * DIN + k] * xv;
        ab += A.Wih[(tid + 512) * DIN + k] * xv;
      }
      for (int k = 0; k < HS; ++k) {
        float hv = sm.hprev[k];
        aa += A.Whh[tid * HS + k] * hv;
        ab += A.Whh[(tid + 512) * HS + k] * hv;
      }
    }
    sm.garr[tid] = aa;
    sm.garr[tid + 512] = ab;
    __syncthreads();

    // ---- LSTM cell update (unit per thread, c in registers) ----
    if (tid < HS) {
      float gi = sm.garr[tid], gf = sm.garr[HS + tid];
      float gg = sm.garr[2 * HS + tid], go = sm.garr[3 * HS + tid];
      float cn = sigf(gf) * c_r + sigf(gi) * tanhf(gg);
      c_r = cn;
      sm.lstm_h[tid] = sigf(go) * tanhf(cn);
    }
    __syncthreads();

    // ---- pack z0 = [x(13), lstm_h[0..77)] ----
    if (PK && tid < 45) {
      int k = 2 * tid;
      float s0 = (k < DIN) ? sm.xt[k] : sm.lstm_h[k - DIN];
      ++k;
      float s1 = (k < DIN) ? sm.xt[k] : sm.lstm_h[k - DIN];
      z0u[tid] = pk2(s0, s1);
    }
    __syncthreads();

    // ---- l0 matvec (308 rows, K=90) ----
    if (tid < NR0) {
      int mat = tid / N0, o = tid % N0;
      float acc = sm.cb0[tid];
      if (PK) {
#pragma unroll
        for (int q = 0; q < Q0; ++q) acc = dot8f(sm.ld0[q * NR0 + tid], sm.z0[q], acc);
      } else {
        const float* W = A.W0[mat];
        const float* m = A.m0;
        const int Kl = DIN + N0;
        for (int k = 0; k < DIN; ++k) {
          float w = W[o * Kl + k];
          if (mat < 2) w *= m[o * Kl + k];
          acc += w * sm.xt[k];
        }
        for (int k = DIN; k < Kl; ++k) acc += W[o * Kl + k] * sm.lstm_h[k - DIN];
      }
      sm.ffb[mat][o] = (mat < 2) ? tanhf(acc) : acc;
    }
    __syncthreads();
    if (tid < N0) {
      float ti = sigf(sm.ffb[2][tid] + sm.ffb[3][tid]);
      sm.hprev[tid] = sm.ffb[0][tid] * (1.f - ti) + ti * sm.ffb[1][tid];
    }
    __syncthreads();

    // ---- pack z1 = [l0_out(77), lstm_h[77..128)] ----
    if (PK && tid < Q1 * 4) {
      int k = 2 * tid;
      float s0 = (k < N0) ? sm.hprev[k] : sm.lstm_h[k];
      ++k;
      float s1 = (k < N0) ? sm.hprev[k] : sm.lstm_h[k];
      z1u[tid] = pk2(s0, s1);
    }
    __syncthreads();

    // ---- l1 matvec (204 rows, K=128) ----
    if (tid < NR1) {
      int mat = tid / N1, o = tid % N1;
      float acc = sm.cb1[tid];
      if (PK) {
#pragma unroll
        for (int q = 0; q < Q1; ++q) acc = dot8f(sm.ld1[q * NR1 + tid], sm.z1[q], acc);
      } else {
        const float* W = A.W1[mat];
        const float* m = A.m1;
        const int Kl = N0 + N1;
        for (int k = 0; k < N0; ++k) {
          float w = W[o * Kl + k];
          if (mat < 2) w *= m[o * Kl + k];
          acc += w * sm.hprev[k];
        }
        for (int k = N0; k < Kl; ++k) acc += W[o * Kl + k] * sm.lstm_h[k];
      }
      sm.ffb[mat][o] = (mat < 2) ? tanhf(acc) : acc;
    }
    __syncthreads();
    if (tid < N1) {
      float ti = sigf(sm.ffb[2][tid] + sm.ffb[3][tid]);
      sm.hprev[N0 + tid] = sm.ffb[0][tid] * (1.f - ti) + ti * sm.ffb[1][tid];
    }
    __syncthreads();

    // ---- pack z2 = [l1_out(51), lstm_h[128..256), pad] ----
    if (PK && tid < 90) {
      int k = 2 * tid;
      float s0 = (k < N1) ? sm.hprev[N0 + k] : sm.lstm_h[N0 + k];
      ++k;
      float s1 = (k >= KL2) ? 0.f : ((k < N1) ? sm.hprev[N0 + k] : sm.lstm_h[N0 + k]);
      z2u[tid] = pk2(s0, s1);
    }
    __syncthreads();

    // ---- l2 matvec (512 rows, K=179, weights streamed from L2) ----
    {
      int mat = tid >> 7, o = tid & 127;
      float acc = sm.cb2[tid];
      if (PK) {
#pragma unroll 4
        for (int q = 0; q < Q2; ++q) acc = dot8f(A.wsL2[q * NR2 + tid], sm.z2[q], acc);
      } else {
        const float* W = A.W2[mat];
        const float* m = A.m2;
        const int Kl = N1 + N2;
        for (int k = 0; k < N1; ++k) {
          float w = W[o * Kl + k];
          if (mat < 2) w *= m[o * Kl + k];
          acc += w * sm.hprev[N0 + k];
        }
        for (int k = N1; k < Kl; ++k) acc += W[o * Kl + k] * sm.lstm_h[N0 + k];
      }
      sm.ffb[mat][o] = (mat < 2) ? tanhf(acc) : acc;
    }
    __syncthreads();
    if (tid < N2) {
      float ti = sigf(sm.ffb[2][tid] + sm.ffb[3][tid]);
      sm.hprev[N0 + N1 + tid] = sm.ffb[0][tid] * (1.f - ti) + ti * sm.ffb[1][tid];
    }
    __syncthreads();

    // ---- heads (threads 256..267) + repack z2g h-part (threads 0..127) ----
    if (tid >= 256 && tid < 268) {
      int r = tid - 256;
      const float* mo = &sm.hprev[N0 + N1];
      float acc = sm.hb[r];
      for (int k = 0; k < 128; ++k) acc += sm.hw[r][k] * mo[k];
      size_t base = ((size_t)b * T_ + t) * 6;
      if (r < 6) {
        outP[base + r] = acc;
      } else {
        float sp = (acc > 0.f) ? (acc + log1pf(expf(-acc))) : log1pf(expf(acc));
        outP[UNC_OFF + base + (r - 6)] = sp;
      }
    }
    if (PK && tid < 128) {
      zgu[7 + tid] = pk2(sm.hprev[2 * tid], sm.hprev[2 * tid + 1]);
    }
    __syncthreads();
  }
}

// ---------------- launcher ----------------

extern "C" void kernel_launch(void* const* d_in, const int* in_sizes, int n_in,
                              void* d_out, int out_size, void* d_ws, size_t ws_size,
                              hipStream_t stream) {
  Args A;
  A.x   = (const float*)d_in[0];
  A.Wih = (const float*)d_in[1];
  A.Whh = (const float*)d_in[2];
  A.bih = (const float*)d_in[3];
  A.bhh = (const float*)d_in[4];
  const float** Wl[3] = {A.W0, A.W1, A.W2};
  const float** bl[3] = {A.b0, A.b1, A.b2};
  const float* ml[3];
  for (int l = 0; l < 3; ++l) {
    int base = 5 + l * 9;
    for (int nm = 0; nm < 4; ++nm) {
      Wl[l][nm] = (const float*)d_in[base + 2 * nm];
      bl[l][nm] = (const float*)d_in[base + 2 * nm + 1];
    }
    ml[l] = (const float*)d_in[base + 8];
  }
  A.m0 = ml[0]; A.m1 = ml[1]; A.m2 = ml[2];
  A.gW = (const float*)d_in[32];
  A.gb = (const float*)d_in[33];
  A.aW = (const float*)d_in[34];
  A.ab = (const float*)d_in[35];
  A.uW = (const float*)d_in[36];
  A.ub = (const float*)d_in[37];
  A.out = (float*)d_out;

  const size_t szG  = (size_t)QG * NRG * 16;   // 557056
  const size_t szL0 = (size_t)Q0 * NR0 * 16;   // 59136
  const size_t szL1 = (size_t)Q1 * NR1 * 16;   // 52224
  const size_t szL2 = (size_t)Q2 * NR2 * 16;   // 196608
  const size_t offG = 0, offL0 = szG, offL1 = offL0 + szL0, offL2 = offL1 + szL1;
  const size_t need = offL2 + szL2;            // 865024

  char* ws = (char*)d_ws;
  A.wsG  = (const uint4*)(ws + offG);
  A.wsL0 = (const uint4*)(ws + offL0);
  A.wsL1 = (const uint4*)(ws + offL1);
  A.wsL2 = (const uint4*)(ws + offL2);

  const bool pk = (ws_size >= need);

  if (pk) {
    int n;
    n = K2G * NRG;
    prep_gates<<<(n + 255) / 256, 256, 0, stream>>>(A.Wih, A.Whh, (uint32_t*)(ws + offG));
    n = NR0 * K2_0;
    prep_cfc<<<(n + 255) / 256, 256, 0, stream>>>(A.W0[0], A.W0[1], A.W0[2], A.W0[3], A.m0,
                                                  N0, DIN, NR0, K2_0, (uint32_t*)(ws + offL0));
    n = NR1 * K2_1;
    prep_cfc<<<(n + 255) / 256, 256, 0, stream>>>(A.W1[0], A.W1[1], A.W1[2], A.W1[3], A.m1,
                                                  N1, N0, NR1, K2_1, (uint32_t*)(ws + offL1));
    n = NR2 * K2_2;
    prep_cfc<<<(n + 255) / 256, 256, 0, stream>>>(A.W2[0], A.W2[1], A.W2[2], A.W2[3], A.m2,
                                                  N2, N1, NR2, K2_2, (uint32_t*)(ws + offL2));
    hipFuncSetAttribute(reinterpret_cast<const void*>(&rnn_persist<true>),
                        hipFuncAttributeMaxDynamicSharedMemorySize, (int)sizeof(SM));
    rnn_persist<true><<<B_, 512, sizeof(SM), stream>>>(A);
  } else {
    hipFuncSetAttribute(reinterpret_cast<const void*>(&rnn_persist<false>),
                        hipFuncAttributeMaxDynamicSharedMemorySize, (int)sizeof(SM));
    rnn_persist<false><<<B_, 512, sizeof(SM), stream>>>(A);
  }
}